// Round 8
// baseline (318.410 us; speedup 1.0000x reference)
//
#include <hip/hip_runtime.h>
#include <hip/hip_bf16.h>
#include <math.h>

#define N_GRAPHS 256
#define NODES_PER 100
#define NN (N_GRAPHS * NODES_PER)   // 25600
#define DEG 8
#define FD 128
#define LAT 256
#define HFD 512                      // HEADS * F_DIM
#define NEG_SLOPE 0.2f

typedef _Float16 half8 __attribute__((ext_vector_type(8)));
typedef float float4v __attribute__((ext_vector_type(4)));

// XCD-contiguous chunk swizzle; requires total % 8 == 0 (bijective)
__device__ __forceinline__ int xcd_swz(int bid, int total) {
    int q = total >> 3;
    return (bid & 7) * q + (bid >> 3);
}

// async global->LDS, 16 bytes per lane; lds base must be wave-uniform
__device__ __forceinline__ void gload_lds16(const _Float16* g, _Float16* l) {
    __builtin_amdgcn_global_load_lds(
        (const __attribute__((address_space(1))) unsigned int*)g,
        (__attribute__((address_space(3))) unsigned int*)l, 16, 0, 0);
}

// ---------------------------------------------------------------- g0 = z @ W0 + b0   [256,128]
__global__ void g0_kernel(const float* __restrict__ z, const float* __restrict__ W0,
                          const float* __restrict__ b0, float* __restrict__ g0) {
    __shared__ float s_z[LAT];
    int g = blockIdx.x;
    int j = threadIdx.x;
    s_z[j]       = z[g * LAT + j];
    s_z[j + 128] = z[g * LAT + 128 + j];
    __syncthreads();
    float acc = 0.f;
    #pragma unroll 8
    for (int k = 0; k < LAT; ++k)
        acc += s_z[k] * W0[k * FD + j];
    g0[g * FD + j] = acc + b0[j];
}

// ---------------------------------------------------------------- x1 = relu(concat(g0[batch], pos[order]))  [N,256] fp16
__global__ void build_x1_kernel(const float* __restrict__ g0,
                                const int* __restrict__ batch, _Float16* __restrict__ x1) {
    __shared__ int s_b, s_ord;
    int i = blockIdx.x;
    int t = threadIdx.x;
    if (t == 0) {
        int b = batch[i];
        int lo = 0, hi = i;
        while (lo < hi) { int mid = (lo + hi) >> 1; if (batch[mid] < b) lo = mid + 1; else hi = mid; }
        s_b = b;
        s_ord = i - lo;
    }
    __syncthreads();
    float v;
    if (t < 128) {
        v = g0[s_b * FD + t];
    } else {
        int j = t - 128;
        int j2 = j >> 1;
        float freq = expf(-(float)j2 * 0.1439115683f);   // ln(10000)/64
        float ang = (float)s_ord * freq;
        v = (j & 1) ? cosf(ang) : sinf(ang);
    }
    x1[(size_t)i * 256 + t] = (_Float16)fmaxf(v, 0.f);
}

// ---------------------------------------------------------------- merged weight transpose+convert (4 matrices, one launch)
__global__ void wconv_all_kernel(const float* __restrict__ W1, const float* __restrict__ W2,
                                 const float* __restrict__ W3, const float* __restrict__ Wg,
                                 _Float16* __restrict__ W1t, _Float16* __restrict__ W2t,
                                 _Float16* __restrict__ W3t, _Float16* __restrict__ Wgt) {
    __shared__ float tile[32][33];
    int b = blockIdx.x;
    const float* in; _Float16* out; int K, Nw, tid2;
    if (b < 128)      { in = W1; out = W1t; K = 256; Nw = 512; tid2 = b; }
    else if (b < 384) { in = W2; out = W2t; K = 512; Nw = 512; tid2 = b - 128; }
    else if (b < 640) { in = W3; out = W3t; K = 512; Nw = 512; tid2 = b - 384; }
    else              { in = Wg; out = Wgt; K = 512; Nw = 128; tid2 = b - 640; }
    int nxt = Nw / 32;
    int nb = (tid2 % nxt) * 32, kb = (tid2 / nxt) * 32;
    int tx = threadIdx.x & 31, ty = threadIdx.x >> 5;
    #pragma unroll
    for (int r = 0; r < 4; ++r)
        tile[ty + 8 * r][tx] = in[(size_t)(kb + ty + 8 * r) * Nw + nb + tx];
    __syncthreads();
    #pragma unroll
    for (int r = 0; r < 4; ++r)
        out[(size_t)(nb + ty + 8 * r) * K + kb + tx] = (_Float16)tile[tx][ty + 8 * r];
}

// ---------------------------------------------------------------- fused GAT layer: one block = one graph (100 nodes)
// Phase 1: Y[100+pad][512] = X[rows][K] @ Wt^T  (A via global_load_lds, B frags direct from L2)
// Phase 2: s,d from f32 accumulators; Y -> LDS (XOR-chunk-swizzled)
// Phase 3: per-node 9-edge softmax + aggregate from LDS -> Xout (global, fp16)
template <int K>
__global__ __launch_bounds__(512, 2) void gat_fused_kernel(
    const _Float16* __restrict__ X,    // [*][K] row-major
    const _Float16* __restrict__ Wt,   // [512][K] row-major
    const float* __restrict__ a_src,   // [512]  ([4][128])
    const float* __restrict__ a_dst,   // [512]
    const int* __restrict__ esrc,      // [NN*8] global src ids
    const float* __restrict__ bias,    // [512]
    _Float16* __restrict__ Xout) {     // [NN][512]
    __shared__ __align__(16) _Float16 As[128 * 32];     // 8 KB, one K-step A-tile
    __shared__ __align__(16) _Float16 Ylds[100 * 512];  // 100 KB, chunk-swizzled
    __shared__ float sdpart[112][8][2];                 // 7 KB
    __shared__ float s_lds[112][4];
    __shared__ float d_lds[112][4];

    const int g    = blockIdx.x;
    const int tid  = threadIdx.x;
    const int lane = tid & 63;
    const int wc   = tid >> 6;        // wave = 64-col slice
    const int kq   = lane >> 4;
    const int l15  = lane & 15;
    const int rowbase = g * NODES_PER;

    // ---- phase 1: GEMM
    const int srow = tid >> 2;                        // 0..127
    const int sq   = (tid & 3) ^ ((tid >> 3) & 3);    // pre-swizzled k-chunk
    const _Float16* gA = X + (size_t)(rowbase + srow) * K + sq * 8;
    _Float16* ldsA = &As[wc * 512];                   // wave-uniform base

    const _Float16* gW[4];
    #pragma unroll
    for (int ni = 0; ni < 4; ++ni) {
        int c = wc * 64 + ni * 16 + l15;
        gW[ni] = Wt + (size_t)c * K + kq * 8;
    }

    float4v acc[7][4];
    #pragma unroll
    for (int mi = 0; mi < 7; ++mi)
        #pragma unroll
        for (int ni = 0; ni < 4; ++ni)
            acc[mi][ni] = (float4v){0.f, 0.f, 0.f, 0.f};

    const int nk = K >> 5;
    for (int ks = 0; ks < nk; ++ks) {
        gload_lds16(gA + ks * 32, ldsA);
        half8 bfr[4];
        #pragma unroll
        for (int ni = 0; ni < 4; ++ni)
            bfr[ni] = *(const half8*)(gW[ni] + ks * 32);
        __syncthreads();                 // drains vmcnt: A tile + bfr ready
        half8 af[7];
        #pragma unroll
        for (int mi = 0; mi < 7; ++mi) {
            int r = mi * 16 + l15;
            af[mi] = *(const half8*)&As[r * 32 + ((kq ^ ((r >> 1) & 3)) * 8)];
        }
        #pragma unroll
        for (int mi = 0; mi < 7; ++mi)
            #pragma unroll
            for (int ni = 0; ni < 4; ++ni)
                acc[mi][ni] = __builtin_amdgcn_mfma_f32_16x16x32_f16(af[mi], bfr[ni], acc[mi][ni], 0, 0, 0);
        __syncthreads();                 // A reads done before next DMA
    }

    // ---- phase 2: Y -> LDS (swizzled) + s,d partials
    float asv[4], adv[4];
    #pragma unroll
    for (int ni = 0; ni < 4; ++ni) {
        int c = wc * 64 + ni * 16 + l15;
        asv[ni] = a_src[c];
        adv[ni] = a_dst[c];
    }
    const int hi4 = lane >> 4;
    #pragma unroll
    for (int mi = 0; mi < 7; ++mi) {
        #pragma unroll
        for (int j = 0; j < 4; ++j) {
            int r = mi * 16 + hi4 * 4 + j;
            float ps = 0.f, pd = 0.f;
            #pragma unroll
            for (int ni = 0; ni < 4; ++ni) {
                float v = acc[mi][ni][j];
                ps += v * asv[ni];
                pd += v * adv[ni];
                if (r < NODES_PER) {
                    int c = wc * 64 + ni * 16 + l15;
                    Ylds[r * 512 + (((c >> 3) ^ (r & 7)) * 8) + (c & 7)] = (_Float16)v;
                }
            }
            #pragma unroll
            for (int m = 8; m >= 1; m >>= 1) {
                ps += __shfl_xor(ps, m);
                pd += __shfl_xor(pd, m);
            }
            if (l15 == 0) {
                sdpart[r][wc][0] = ps;
                sdpart[r][wc][1] = pd;
            }
        }
    }
    __syncthreads();
    if (tid < 448) {
        int r = tid >> 2, h = tid & 3;
        s_lds[r][h] = sdpart[r][2 * h][0] + sdpart[r][2 * h + 1][0];
        d_lds[r][h] = sdpart[r][2 * h][1] + sdpart[r][2 * h + 1][1];
    }
    __syncthreads();

    // ---- phase 3: attention + aggregate (wave per node, strided)
    const int hd = lane >> 4;        // head of this lane's cols
    const int c0 = lane * 8;
    float4v b0 = *(const float4v*)&bias[c0];
    float4v b1 = *(const float4v*)&bias[c0 + 4];
    for (int i = wc; i < NODES_PER; i += 8) {
        int sg = (lane < 8) ? (esrc[(size_t)(rowbase + i) * DEG + lane] - rowbase) : i;
        int sl[9];
        #pragma unroll
        for (int k = 0; k < 9; ++k) sl[k] = __shfl(sg, k);   // k=8 -> lane 8 -> i (self)
        float dh = d_lds[i][hd];
        float e[9];
        float mx = -1e30f;
        #pragma unroll
        for (int k = 0; k < 9; ++k) {
            float v = s_lds[sl[k]][hd] + dh;
            v = (v >= 0.f) ? v : NEG_SLOPE * v;
            e[k] = v;
            mx = fmaxf(mx, v);
        }
        float den = 0.f;
        #pragma unroll
        for (int k = 0; k < 9; ++k) { e[k] = __expf(e[k] - mx); den += e[k]; }
        float inv = 1.f / (den + 1e-16f);
        float a8[8] = {};
        #pragma unroll
        for (int k = 0; k < 9; ++k) {
            half8 y = *(const half8*)&Ylds[sl[k] * 512 + ((lane ^ (sl[k] & 7)) * 8)];
            float a = e[k] * inv;
            #pragma unroll
            for (int j = 0; j < 8; ++j) a8[j] += a * (float)y[j];
        }
        half8 o;
        #pragma unroll
        for (int j = 0; j < 4; ++j) {
            o[j]     = (_Float16)fmaxf(a8[j] + b0[j], 0.f);
            o[j + 4] = (_Float16)fmaxf(a8[j + 4] + b1[j], 0.f);
        }
        *(half8*)&Xout[(size_t)(rowbase + i) * HFD + c0] = o;
    }
}

// ---------------------------------------------------------------- head: out = relu(X@Wgt+bg) @ Wf + bf  [N,5] f32
__global__ __launch_bounds__(256) void head_kernel(
    const _Float16* __restrict__ X,   // [NN][512]
    const _Float16* __restrict__ Wt,  // [128][512]
    const float* __restrict__ bias,   // bg[128]
    const float* __restrict__ Wf,     // [128][5]
    const float* __restrict__ bfv,    // [5]
    float* __restrict__ out) {
    __shared__ __align__(16) _Float16 As[128 * 32];
    __shared__ __align__(16) _Float16 Bs[128 * 32];
    __shared__ float red[5][128][2];
    const int lin = xcd_swz(blockIdx.x, gridDim.x);
    const int row0 = lin * 128;
    const int tid  = threadIdx.x;
    const int lane = tid & 63;
    const int wave = tid >> 6;
    const int wm = wave >> 1;
    const int wn = wave & 1;
    const int K = 512;

    const int srow = tid >> 2;
    const int sq   = (tid & 3) ^ ((tid >> 3) & 3);
    const _Float16* gA0 = X  + (size_t)(row0 + srow) * K + sq * 8;
    const _Float16* gB0 = Wt + (size_t)srow * K + sq * 8;
    const _Float16* gA1 = gA0 + (size_t)64 * K;
    const _Float16* gB1 = gB0 + (size_t)64 * K;
    _Float16* ldsA0 = &As[wave * 512];
    _Float16* ldsA1 = &As[2048 + wave * 512];
    _Float16* ldsB0 = &Bs[wave * 512];
    _Float16* ldsB1 = &Bs[2048 + wave * 512];

    const int kq  = lane >> 4;
    const int l15 = lane & 15;

    float4v acc[4][4];
    #pragma unroll
    for (int i = 0; i < 4; ++i)
        #pragma unroll
        for (int j = 0; j < 4; ++j)
            acc[i][j] = (float4v){0.f, 0.f, 0.f, 0.f};

    for (int ks = 0; ks < 16; ++ks) {
        gload_lds16(gA0 + ks * 32, ldsA0);
        gload_lds16(gA1 + ks * 32, ldsA1);
        gload_lds16(gB0 + ks * 32, ldsB0);
        gload_lds16(gB1 + ks * 32, ldsB1);
        __syncthreads();
        half8 af[4], bfr[4];
        #pragma unroll
        for (int mi = 0; mi < 4; ++mi) {
            int r = wm * 64 + mi * 16 + l15;
            af[mi] = *(const half8*)&As[r * 32 + ((kq ^ ((r >> 1) & 3)) * 8)];
        }
        #pragma unroll
        for (int ni = 0; ni < 4; ++ni) {
            int c = wn * 64 + ni * 16 + l15;
            bfr[ni] = *(const half8*)&Bs[c * 32 + ((kq ^ ((c >> 1) & 3)) * 8)];
        }
        #pragma unroll
        for (int mi = 0; mi < 4; ++mi)
            #pragma unroll
            for (int ni = 0; ni < 4; ++ni)
                acc[mi][ni] = __builtin_amdgcn_mfma_f32_16x16x32_f16(af[mi], bfr[ni], acc[mi][ni], 0, 0, 0);
        __syncthreads();
    }

    float bgv[4], wf[4][5];
    #pragma unroll
    for (int ni = 0; ni < 4; ++ni) {
        int c = wn * 64 + ni * 16 + l15;
        bgv[ni] = bias[c];
        #pragma unroll
        for (int q = 0; q < 5; ++q) wf[ni][q] = Wf[c * 5 + q];
    }
    #pragma unroll
    for (int mi = 0; mi < 4; ++mi) {
        #pragma unroll
        for (int j = 0; j < 4; ++j) {
            float vr[4];
            #pragma unroll
            for (int ni = 0; ni < 4; ++ni)
                vr[ni] = fmaxf(acc[mi][ni][j] + bgv[ni], 0.f);
            #pragma unroll
            for (int q = 0; q < 5; ++q) {
                float p = vr[0] * wf[0][q] + vr[1] * wf[1][q] + vr[2] * wf[2][q] + vr[3] * wf[3][q];
                #pragma unroll
                for (int m = 8; m >= 1; m >>= 1) p += __shfl_xor(p, m);
                if (l15 == 0) {
                    int rloc = wm * 64 + mi * 16 + ((lane >> 4) << 2) + j;
                    red[q][rloc][wn] = p;
                }
            }
        }
    }
    __syncthreads();
    if (tid < 128) {
        #pragma unroll
        for (int q = 0; q < 5; ++q)
            out[(size_t)(row0 + tid) * 5 + q] = red[q][tid][0] + red[q][tid][1] + bfv[q];
    }
}

// ----------------------------------------------------------------
extern "C" void kernel_launch(void* const* d_in, const int* in_sizes, int n_in,
                              void* d_out, int out_size, void* d_ws, size_t ws_size,
                              hipStream_t stream) {
    const float* z    = (const float*)d_in[0];
    const int*  eidx  = (const int*)d_in[1];
    const int*  batch = (const int*)d_in[2];
    const float* W0  = (const float*)d_in[3];
    const float* b0  = (const float*)d_in[4];
    const float* W1  = (const float*)d_in[5];
    const float* as1 = (const float*)d_in[6];
    const float* ad1 = (const float*)d_in[7];
    const float* b1  = (const float*)d_in[8];
    const float* W2  = (const float*)d_in[9];
    const float* as2 = (const float*)d_in[10];
    const float* ad2 = (const float*)d_in[11];
    const float* b2  = (const float*)d_in[12];
    const float* W3  = (const float*)d_in[13];
    const float* as3 = (const float*)d_in[14];
    const float* ad3 = (const float*)d_in[15];
    const float* b3  = (const float*)d_in[16];
    const float* Wg  = (const float*)d_in[17];
    const float* bg  = (const float*)d_in[18];
    const float* Wf  = (const float*)d_in[19];
    const float* bfv = (const float*)d_in[20];
    float* out = (float*)d_out;

    float* ws   = (float*)d_ws;
    float* g0   = ws;                                      // 32768 f32
    _Float16* Xh1 = (_Float16*)(g0 + 32768);               // NN*256 fp16
    _Float16* Xa  = Xh1 + (size_t)NN * 256;                // NN*512 fp16
    _Float16* Xb  = Xa + (size_t)NN * 512;                 // NN*512 fp16
    _Float16* W1t = Xb + (size_t)NN * 512;                 // 512*256
    _Float16* W2t = W1t + 512 * 256;                       // 512*512
    _Float16* W3t = W2t + 512 * 512;                       // 512*512
    _Float16* Wgt = W3t + 512 * 512;                       // 128*512

    g0_kernel<<<N_GRAPHS, FD, 0, stream>>>(z, W0, b0, g0);
    build_x1_kernel<<<NN, 256, 0, stream>>>(g0, batch, Xh1);
    wconv_all_kernel<<<704, 256, 0, stream>>>(W1, W2, W3, Wg, W1t, W2t, W3t, Wgt);

    // fused layers: one block per graph
    gat_fused_kernel<256><<<N_GRAPHS, 512, 0, stream>>>(Xh1, W1t, as1, ad1, eidx, b1, Xa);
    gat_fused_kernel<512><<<N_GRAPHS, 512, 0, stream>>>(Xa,  W2t, as2, ad2, eidx, b2, Xb);
    gat_fused_kernel<512><<<N_GRAPHS, 512, 0, stream>>>(Xb,  W3t, as3, ad3, eidx, b3, Xa);

    // head + final projection
    head_kernel<<<NN / 128, 256, 0, stream>>>(Xa, Wgt, bg, Wf, bfv, out);
}

// Round 9
// 314.286 us; speedup vs baseline: 1.0131x; 1.0131x over previous
//
#include <hip/hip_runtime.h>
#include <hip/hip_bf16.h>
#include <math.h>

#define N_GRAPHS 256
#define NODES_PER 100
#define NN (N_GRAPHS * NODES_PER)   // 25600
#define DEG 8
#define FD 128
#define LAT 256
#define HFD 512                      // HEADS * F_DIM
#define NEG_SLOPE 0.2f

typedef _Float16 half8 __attribute__((ext_vector_type(8)));
typedef float float4v __attribute__((ext_vector_type(4)));

// XCD-contiguous chunk swizzle; requires total % 8 == 0 (bijective)
__device__ __forceinline__ int xcd_swz(int bid, int total) {
    int q = total >> 3;
    return (bid & 7) * q + (bid >> 3);
}

// async global->LDS, 16 bytes per lane; lds base must be wave-uniform
__device__ __forceinline__ void gload_lds16(const _Float16* g, _Float16* l) {
    __builtin_amdgcn_global_load_lds(
        (const __attribute__((address_space(1))) unsigned int*)g,
        (__attribute__((address_space(3))) unsigned int*)l, 16, 0, 0);
}

// ---------------------------------------------------------------- g0 = z @ W0 + b0   [256,128]
__global__ void g0_kernel(const float* __restrict__ z, const float* __restrict__ W0,
                          const float* __restrict__ b0, float* __restrict__ g0) {
    __shared__ float s_z[LAT];
    int g = blockIdx.x;
    int j = threadIdx.x;
    s_z[j]       = z[g * LAT + j];
    s_z[j + 128] = z[g * LAT + 128 + j];
    __syncthreads();
    float acc = 0.f;
    #pragma unroll 8
    for (int k = 0; k < LAT; ++k)
        acc += s_z[k] * W0[k * FD + j];
    g0[g * FD + j] = acc + b0[j];
}

// ---------------------------------------------------------------- x1 = relu(concat(g0[batch], pos[order]))  [N,256] fp16
__global__ void build_x1_kernel(const float* __restrict__ g0,
                                const int* __restrict__ batch, _Float16* __restrict__ x1) {
    __shared__ int s_b, s_ord;
    int i = blockIdx.x;
    int t = threadIdx.x;
    if (t == 0) {
        int b = batch[i];
        int lo = 0, hi = i;
        while (lo < hi) { int mid = (lo + hi) >> 1; if (batch[mid] < b) lo = mid + 1; else hi = mid; }
        s_b = b;
        s_ord = i - lo;
    }
    __syncthreads();
    float v;
    if (t < 128) {
        v = g0[s_b * FD + t];
    } else {
        int j = t - 128;
        int j2 = j >> 1;
        float freq = expf(-(float)j2 * 0.1439115683f);   // ln(10000)/64
        float ang = (float)s_ord * freq;
        v = (j & 1) ? cosf(ang) : sinf(ang);
    }
    x1[(size_t)i * 256 + t] = (_Float16)fmaxf(v, 0.f);
}

// ---------------------------------------------------------------- merged weight transpose+convert (4 matrices, one launch)
__global__ void wconv_all_kernel(const float* __restrict__ W1, const float* __restrict__ W2,
                                 const float* __restrict__ W3, const float* __restrict__ Wg,
                                 _Float16* __restrict__ W1t, _Float16* __restrict__ W2t,
                                 _Float16* __restrict__ W3t, _Float16* __restrict__ Wgt) {
    __shared__ float tile[32][33];
    int b = blockIdx.x;
    const float* in; _Float16* out; int K, Nw, tid2;
    if (b < 128)      { in = W1; out = W1t; K = 256; Nw = 512; tid2 = b; }
    else if (b < 384) { in = W2; out = W2t; K = 512; Nw = 512; tid2 = b - 128; }
    else if (b < 640) { in = W3; out = W3t; K = 512; Nw = 512; tid2 = b - 384; }
    else              { in = Wg; out = Wgt; K = 512; Nw = 128; tid2 = b - 640; }
    int nxt = Nw / 32;
    int nb = (tid2 % nxt) * 32, kb = (tid2 / nxt) * 32;
    int tx = threadIdx.x & 31, ty = threadIdx.x >> 5;
    #pragma unroll
    for (int r = 0; r < 4; ++r)
        tile[ty + 8 * r][tx] = in[(size_t)(kb + ty + 8 * r) * Nw + nb + tx];
    __syncthreads();
    #pragma unroll
    for (int r = 0; r < 4; ++r)
        out[(size_t)(nb + ty + 8 * r) * K + kb + tx] = (_Float16)tile[tx][ty + 8 * r];
}

// ---------------------------------------------------------------- fused GAT layer, block = (graph, head)
// Phase 1: Y_h[100][128] = X[g][100][K] @ W_h^T  (A via global_load_lds, B frags from L2)
// Phase 2: s,d (head h) from f32 acc; Y_h -> LDS (16-chunk XOR swizzle)
// Phase 3: 9-edge softmax + aggregate for head-h cols -> Xout
// blockIdx mapping: xcd = bid&7, slot = bid>>3; graph = xcd*32 + slot>>2, head = slot&3
// (4 head-blocks of a graph land on one XCD -> X L2-shared)
template <int K>
__global__ __launch_bounds__(256, 4) void gat2_kernel(
    const _Float16* __restrict__ X,    // [*][K] row-major (28 rows slack past NN)
    const _Float16* __restrict__ Wt,   // [512][K] row-major
    const float* __restrict__ a_src,   // [512]
    const float* __restrict__ a_dst,   // [512]
    const int* __restrict__ esrc,      // [NN*8] global src ids
    const float* __restrict__ bias,    // [512]
    _Float16* __restrict__ Xout) {     // [NN][512]
    __shared__ __align__(16) _Float16 As[128 * 32];     // 8 KB
    __shared__ __align__(16) _Float16 Ylds[100 * 128];  // 25.6 KB, chunk-swizzled
    __shared__ float sdp[112][4][2];                    // 3.5 KB
    __shared__ float s_lds[112], d_lds[112];

    const int b    = blockIdx.x;
    const int g    = (b & 7) * 32 + ((b >> 3) >> 2);
    const int h    = (b >> 3) & 3;
    const int rowbase = g * NODES_PER;
    const int tid  = threadIdx.x;
    const int lane = tid & 63;
    const int wc   = tid >> 6;        // wave = 32-col slice of head h
    const int kq   = lane >> 4;
    const int l15  = lane & 15;

    // ---- phase 1: GEMM
    const int srow = tid >> 2;                        // 0..63
    const int sq   = (tid & 3) ^ ((tid >> 3) & 3);    // pre-swizzled k-chunk
    const _Float16* gA0 = X + (size_t)(rowbase + srow) * K + sq * 8;
    const _Float16* gA1 = gA0 + (size_t)64 * K;
    _Float16* ldsA0 = &As[wc * 512];
    _Float16* ldsA1 = &As[2048 + wc * 512];

    const _Float16* gW0 = Wt + (size_t)(h * 128 + wc * 32 + l15) * K + kq * 8;
    const _Float16* gW1 = gW0 + (size_t)16 * K;

    float4v acc[7][2];
    #pragma unroll
    for (int mi = 0; mi < 7; ++mi) {
        acc[mi][0] = (float4v){0.f, 0.f, 0.f, 0.f};
        acc[mi][1] = (float4v){0.f, 0.f, 0.f, 0.f};
    }

    const int nk = K >> 5;
    for (int ks = 0; ks < nk; ++ks) {
        gload_lds16(gA0 + ks * 32, ldsA0);
        gload_lds16(gA1 + ks * 32, ldsA1);
        half8 bf0 = *(const half8*)(gW0 + ks * 32);
        half8 bf1 = *(const half8*)(gW1 + ks * 32);
        __syncthreads();                 // drains vmcnt: A tile ready
        half8 af[7];
        #pragma unroll
        for (int mi = 0; mi < 7; ++mi) {
            int r = mi * 16 + l15;
            af[mi] = *(const half8*)&As[r * 32 + ((kq ^ ((r >> 1) & 3)) * 8)];
        }
        #pragma unroll
        for (int mi = 0; mi < 7; ++mi) {
            acc[mi][0] = __builtin_amdgcn_mfma_f32_16x16x32_f16(af[mi], bf0, acc[mi][0], 0, 0, 0);
            acc[mi][1] = __builtin_amdgcn_mfma_f32_16x16x32_f16(af[mi], bf1, acc[mi][1], 0, 0, 0);
        }
        __syncthreads();                 // A reads done before next DMA
    }

    // ---- phase 2: s,d partials + Y -> LDS (swizzled)
    float asv[2], adv[2];
    #pragma unroll
    for (int ni = 0; ni < 2; ++ni) {
        int c = h * 128 + wc * 32 + ni * 16 + l15;
        asv[ni] = a_src[c];
        adv[ni] = a_dst[c];
    }
    const int hi4 = lane >> 4;
    #pragma unroll
    for (int mi = 0; mi < 7; ++mi) {
        #pragma unroll
        for (int j = 0; j < 4; ++j) {
            int r = mi * 16 + hi4 * 4 + j;
            float ps = acc[mi][0][j] * asv[0] + acc[mi][1][j] * asv[1];
            float pd = acc[mi][0][j] * adv[0] + acc[mi][1][j] * adv[1];
            if (r < NODES_PER) {
                #pragma unroll
                for (int ni = 0; ni < 2; ++ni) {
                    int cl = wc * 32 + ni * 16 + l15;    // local col 0..127
                    Ylds[r * 128 + (((cl >> 3) ^ (r & 15)) * 8) + (cl & 7)] = (_Float16)acc[mi][ni][j];
                }
            }
            #pragma unroll
            for (int m = 8; m >= 1; m >>= 1) {
                ps += __shfl_xor(ps, m);
                pd += __shfl_xor(pd, m);
            }
            if (l15 == 0) {
                sdp[r][wc][0] = ps;
                sdp[r][wc][1] = pd;
            }
        }
    }
    __syncthreads();
    if (tid < 112) {
        s_lds[tid] = sdp[tid][0][0] + sdp[tid][1][0] + sdp[tid][2][0] + sdp[tid][3][0];
        d_lds[tid] = sdp[tid][0][1] + sdp[tid][1][1] + sdp[tid][2][1] + sdp[tid][3][1];
    }
    __syncthreads();

    // ---- phase 3: softmax + aggregate; each wave handles 4 nodes/iter (16 lanes each)
    const int gl   = lane >> 4;       // node subgroup within wave
    const int lsub = lane & 15;       // col chunk within node
    const int shfb = lane & 48;       // shfl group base
    float4v bb0 = *(const float4v*)&bias[h * 128 + lsub * 8];
    float4v bb1 = *(const float4v*)&bias[h * 128 + lsub * 8 + 4];
    #pragma unroll
    for (int it = 0; it < 7; ++it) {
        int i = it * 16 + wc * 4 + gl;
        bool act = (i < NODES_PER);
        int ii = act ? i : (NODES_PER - 1);
        int sg = (lsub < 8) ? (esrc[(size_t)(rowbase + ii) * DEG + lsub] - rowbase) : ii;
        int sl[9];
        #pragma unroll
        for (int k = 0; k < 9; ++k) sl[k] = __shfl(sg, shfb + k);   // k=8 -> lsub 8 -> self
        float dh = d_lds[ii];
        float e[9];
        float mx = -1e30f;
        #pragma unroll
        for (int k = 0; k < 9; ++k) {
            float v = s_lds[sl[k]] + dh;
            v = (v >= 0.f) ? v : NEG_SLOPE * v;
            e[k] = v;
            mx = fmaxf(mx, v);
        }
        float den = 0.f;
        #pragma unroll
        for (int k = 0; k < 9; ++k) { e[k] = __expf(e[k] - mx); den += e[k]; }
        float inv = 1.f / (den + 1e-16f);
        float a8[8] = {};
        #pragma unroll
        for (int k = 0; k < 9; ++k) {
            half8 y = *(const half8*)&Ylds[sl[k] * 128 + ((lsub ^ (sl[k] & 15)) * 8)];
            float a = e[k] * inv;
            #pragma unroll
            for (int j = 0; j < 8; ++j) a8[j] += a * (float)y[j];
        }
        if (act) {
            half8 o;
            #pragma unroll
            for (int j = 0; j < 4; ++j) {
                o[j]     = (_Float16)fmaxf(a8[j] + bb0[j], 0.f);
                o[j + 4] = (_Float16)fmaxf(a8[j + 4] + bb1[j], 0.f);
            }
            *(half8*)&Xout[(size_t)(rowbase + i) * HFD + h * 128 + lsub * 8] = o;
        }
    }
}

// ---------------------------------------------------------------- head: out = relu(X@Wgt+bg) @ Wf + bf  [N,5] f32
__global__ __launch_bounds__(256) void head_kernel(
    const _Float16* __restrict__ X,   // [NN][512]
    const _Float16* __restrict__ Wt,  // [128][512]
    const float* __restrict__ bias,   // bg[128]
    const float* __restrict__ Wf,     // [128][5]
    const float* __restrict__ bfv,    // [5]
    float* __restrict__ out) {
    __shared__ __align__(16) _Float16 As[128 * 32];
    __shared__ __align__(16) _Float16 Bs[128 * 32];
    __shared__ float red[5][128][2];
    const int lin = xcd_swz(blockIdx.x, gridDim.x);
    const int row0 = lin * 128;
    const int tid  = threadIdx.x;
    const int lane = tid & 63;
    const int wave = tid >> 6;
    const int wm = wave >> 1;
    const int wn = wave & 1;
    const int K = 512;

    const int srow = tid >> 2;
    const int sq   = (tid & 3) ^ ((tid >> 3) & 3);
    const _Float16* gA0 = X  + (size_t)(row0 + srow) * K + sq * 8;
    const _Float16* gB0 = Wt + (size_t)srow * K + sq * 8;
    const _Float16* gA1 = gA0 + (size_t)64 * K;
    const _Float16* gB1 = gB0 + (size_t)64 * K;
    _Float16* ldsA0 = &As[wave * 512];
    _Float16* ldsA1 = &As[2048 + wave * 512];
    _Float16* ldsB0 = &Bs[wave * 512];
    _Float16* ldsB1 = &Bs[2048 + wave * 512];

    const int kq  = lane >> 4;
    const int l15 = lane & 15;

    float4v acc[4][4];
    #pragma unroll
    for (int i = 0; i < 4; ++i)
        #pragma unroll
        for (int j = 0; j < 4; ++j)
            acc[i][j] = (float4v){0.f, 0.f, 0.f, 0.f};

    for (int ks = 0; ks < 16; ++ks) {
        gload_lds16(gA0 + ks * 32, ldsA0);
        gload_lds16(gA1 + ks * 32, ldsA1);
        gload_lds16(gB0 + ks * 32, ldsB0);
        gload_lds16(gB1 + ks * 32, ldsB1);
        __syncthreads();
        half8 af[4], bfr[4];
        #pragma unroll
        for (int mi = 0; mi < 4; ++mi) {
            int r = wm * 64 + mi * 16 + l15;
            af[mi] = *(const half8*)&As[r * 32 + ((kq ^ ((r >> 1) & 3)) * 8)];
        }
        #pragma unroll
        for (int ni = 0; ni < 4; ++ni) {
            int c = wn * 64 + ni * 16 + l15;
            bfr[ni] = *(const half8*)&Bs[c * 32 + ((kq ^ ((c >> 1) & 3)) * 8)];
        }
        #pragma unroll
        for (int mi = 0; mi < 4; ++mi)
            #pragma unroll
            for (int ni = 0; ni < 4; ++ni)
                acc[mi][ni] = __builtin_amdgcn_mfma_f32_16x16x32_f16(af[mi], bfr[ni], acc[mi][ni], 0, 0, 0);
        __syncthreads();
    }

    float bgv[4], wf[4][5];
    #pragma unroll
    for (int ni = 0; ni < 4; ++ni) {
        int c = wn * 64 + ni * 16 + l15;
        bgv[ni] = bias[c];
        #pragma unroll
        for (int q = 0; q < 5; ++q) wf[ni][q] = Wf[c * 5 + q];
    }
    #pragma unroll
    for (int mi = 0; mi < 4; ++mi) {
        #pragma unroll
        for (int j = 0; j < 4; ++j) {
            float vr[4];
            #pragma unroll
            for (int ni = 0; ni < 4; ++ni)
                vr[ni] = fmaxf(acc[mi][ni][j] + bgv[ni], 0.f);
            #pragma unroll
            for (int q = 0; q < 5; ++q) {
                float p = vr[0] * wf[0][q] + vr[1] * wf[1][q] + vr[2] * wf[2][q] + vr[3] * wf[3][q];
                #pragma unroll
                for (int m = 8; m >= 1; m >>= 1) p += __shfl_xor(p, m);
                if (l15 == 0) {
                    int rloc = wm * 64 + mi * 16 + ((lane >> 4) << 2) + j;
                    red[q][rloc][wn] = p;
                }
            }
        }
    }
    __syncthreads();
    if (tid < 128) {
        #pragma unroll
        for (int q = 0; q < 5; ++q)
            out[(size_t)(row0 + tid) * 5 + q] = red[q][tid][0] + red[q][tid][1] + bfv[q];
    }
}

// ----------------------------------------------------------------
extern "C" void kernel_launch(void* const* d_in, const int* in_sizes, int n_in,
                              void* d_out, int out_size, void* d_ws, size_t ws_size,
                              hipStream_t stream) {
    const float* z    = (const float*)d_in[0];
    const int*  eidx  = (const int*)d_in[1];
    const int*  batch = (const int*)d_in[2];
    const float* W0  = (const float*)d_in[3];
    const float* b0  = (const float*)d_in[4];
    const float* W1  = (const float*)d_in[5];
    const float* as1 = (const float*)d_in[6];
    const float* ad1 = (const float*)d_in[7];
    const float* b1  = (const float*)d_in[8];
    const float* W2  = (const float*)d_in[9];
    const float* as2 = (const float*)d_in[10];
    const float* ad2 = (const float*)d_in[11];
    const float* b2  = (const float*)d_in[12];
    const float* W3  = (const float*)d_in[13];
    const float* as3 = (const float*)d_in[14];
    const float* ad3 = (const float*)d_in[15];
    const float* b3  = (const float*)d_in[16];
    const float* Wg  = (const float*)d_in[17];
    const float* bg  = (const float*)d_in[18];
    const float* Wf  = (const float*)d_in[19];
    const float* bfv = (const float*)d_in[20];
    float* out = (float*)d_out;

    float* ws   = (float*)d_ws;
    float* g0   = ws;                                      // 32768 f32
    _Float16* Xh1 = (_Float16*)(g0 + 32768);               // NN*256 + slack
    _Float16* Xa  = Xh1 + (size_t)(NN + 128) * 256;        // NN*512 + slack
    _Float16* Xb  = Xa + (size_t)(NN + 128) * 512;         // NN*512 + slack
    _Float16* W1t = Xb + (size_t)(NN + 128) * 512;         // 512*256
    _Float16* W2t = W1t + 512 * 256;                       // 512*512
    _Float16* W3t = W2t + 512 * 512;                       // 512*512
    _Float16* Wgt = W3t + 512 * 512;                       // 128*512

    g0_kernel<<<N_GRAPHS, FD, 0, stream>>>(z, W0, b0, g0);
    build_x1_kernel<<<NN, 256, 0, stream>>>(g0, batch, Xh1);
    wconv_all_kernel<<<704, 256, 0, stream>>>(W1, W2, W3, Wg, W1t, W2t, W3t, Wgt);

    // fused layers: one block per (graph, head)
    gat2_kernel<256><<<N_GRAPHS * 4, 256, 0, stream>>>(Xh1, W1t, as1, ad1, eidx, b1, Xa);
    gat2_kernel<512><<<N_GRAPHS * 4, 256, 0, stream>>>(Xa,  W2t, as2, ad2, eidx, b2, Xb);
    gat2_kernel<512><<<N_GRAPHS * 4, 256, 0, stream>>>(Xb,  W3t, as3, ad3, eidx, b3, Xa);

    // head + final projection
    head_kernel<<<NN / 128, 256, 0, stream>>>(Xa, Wgt, bg, Wf, bfv, out);
}